// Round 3
// baseline (378.007 us; speedup 1.0000x reference)
//
#include <hip/hip_runtime.h>
#include <math.h>

#define B_    32
#define C_    256
#define HF    64
#define WF    64
#define M_    4096   // HF*WF
#define N_    128
#define IMGM1 1023.0f
#define TEMP_ 0.1f
#define EPS_  1e-12f
#define NCH   32     // m-chunks in k2 = M_/128
#define TCH   64     // m-chunk in k0 transpose
#define BKK   64     // K-tile in k2

typedef __attribute__((ext_vector_type(8))) short short8;
typedef __attribute__((ext_vector_type(4))) float floatx4;

__device__ __forceinline__ unsigned short f2bf(float x) {  // RNE fp32->bf16
  unsigned int u = __float_as_uint(x);
  u += 0x7fffu + ((u >> 16) & 1u);
  return (unsigned short)(u >> 16);
}
__device__ __forceinline__ float bf2f(unsigned short h) {
  return __uint_as_float(((unsigned int)h) << 16);
}
__device__ __forceinline__ float wave_sum(float v) {
#pragma unroll
  for (int off = 32; off; off >>= 1) v += __shfl_down(v, off, 64);
  return v;
}
// async global->LDS DMA, 16B per lane; LDS dest = l + lane*16 (wave-uniform l)
__device__ __forceinline__ void gl2lds16(const void* g, void* l) {
  __builtin_amdgcn_global_load_lds((const __attribute__((address_space(1))) unsigned int*)g,
                                   (__attribute__((address_space(3))) unsigned int*)l, 16, 0, 0);
}

__device__ __forceinline__ void src_geom(float kx, float ky, int& x0, int& y0,
                                         int& x1, int& y1, float& fx, float& fy) {
  const float x = kx / IMGM1 * (float)(WF - 1);
  const float y = ky / IMGM1 * (float)(HF - 1);
  x0 = (int)fminf(fmaxf(floorf(x), 0.f), 63.f);
  y0 = (int)fminf(fmaxf(floorf(y), 0.f), 63.f);
  x1 = min(x0 + 1, 63);
  y1 = min(y0 + 1, 63);
  fx = x - (float)x0;
  fy = y - (float)y0;
}

// ============ k0: feats_trg fp32 [b][c][m] -> bf16 transposed [b][m][c] + scl[b][m] ============
// grid (M_/TCH, B_), block 256. Coalesced read, LDS transpose (129-dword row stride), coalesced write.
__global__ __launch_bounds__(256) void k0_trgT(const float* __restrict__ trg,
                                               ushort* __restrict__ trgT,
                                               float* __restrict__ sclg) {
  const int mb = blockIdx.x, b = blockIdx.y, t = threadIdx.x;
  const int m0 = mb * TCH;
  const int cr = t >> 5, ml = t & 31;
  __shared__ unsigned int trdw[TCH * 129];  // 64 rows x 258 shorts (2 pad) = 33 KB
  __shared__ float ssql[8][TCH];

  ushort* trl = (ushort*)trdw;
  const float* tb = trg + (size_t)b * C_ * M_ + m0;
  float sq0 = 0.f, sq1 = 0.f;
  for (int c0 = 0; c0 < C_; c0 += 8) {
    const int c = c0 + cr;
    const float v0 = tb[(size_t)c * M_ + ml];
    const float v1 = tb[(size_t)c * M_ + ml + 32];
    sq0 += v0 * v0;
    sq1 += v1 * v1;
    trl[ml * 258 + c] = f2bf(v0);
    trl[(ml + 32) * 258 + c] = f2bf(v1);
  }
  ssql[cr][ml] = sq0;
  ssql[cr][ml + 32] = sq1;
  __syncthreads();
  if (t < TCH) {
    float s = 0.f;
#pragma unroll
    for (int r = 0; r < 8; r++) s += ssql[r][t];
    sclg[(size_t)b * M_ + m0 + t] = 1.f / (fmaxf(sqrtf(s), EPS_) * TEMP_);
  }
  ushort* outb = trgT + ((size_t)b * M_ + m0) * C_;
#pragma unroll
  for (int it = 0; it < 8; it++) {
    const int flat = it * 256 + t;
    const int m = flat >> 5, ch = flat & 31;
    uint4 d;
    d.x = trdw[m * 129 + ch * 4 + 0];
    d.y = trdw[m * 129 + ch * 4 + 1];
    d.z = trdw[m * 129 + ch * 4 + 2];
    d.w = trdw[m * 129 + ch * 4 + 3];
    *(uint4*)&outb[(size_t)m * C_ + ch * 8] = d;
  }
}

// ============ k1a: coalesced plane staging -> corner gather (bf16) + ssq atomics ============
__global__ __launch_bounds__(256) void k1a_stage(const float* __restrict__ fs,
                                                 const float* __restrict__ kps,
                                                 ushort* __restrict__ corner,
                                                 float* __restrict__ ssqg) {
  const int cg = blockIdx.x, b = blockIdx.y, t = threadIdx.x;
  const int c0 = cg * 2;
  __shared__ __align__(16) float plane[2 * M_];   // 32 KB
  __shared__ float4 ssq2[256];

  const float4* src = (const float4*)(fs + ((size_t)(b * C_ + c0)) * M_);
  float4* dst = (float4*)plane;
#pragma unroll
  for (int i = 0; i < 8; i++) dst[t + 256 * i] = src[t + 256 * i];
  __syncthreads();

  const int n = t & 127, p = t >> 7;
  const int c = c0 + p;
  const float kx = kps[((size_t)b * N_ + n) * 2 + 0];
  const float ky = kps[((size_t)b * N_ + n) * 2 + 1];
  int x0, y0, x1, y1; float fx, fy;
  src_geom(kx, ky, x0, y0, x1, y1, fx, fy);

  const float* pl = plane + p * M_;
  const float f00 = pl[y0 * WF + x0];
  const float f10 = pl[y1 * WF + x0];
  const float f01 = pl[y0 * WF + x1];
  const float f11 = pl[y1 * WF + x1];

  ushort4 cr;
  cr.x = f2bf(f00); cr.y = f2bf(f10); cr.z = f2bf(f01); cr.w = f2bf(f11);
  *(ushort4*)&corner[(((size_t)b * C_ + c) * N_ + n) * 4] = cr;

  ssq2[t] = make_float4(f00 * f00, f10 * f10, f01 * f01, f11 * f11);
  __syncthreads();
  if (t < 128) {
    const float4 a = ssq2[t], bq = ssq2[t + 128];
    float* g = ssqg + ((size_t)b * N_ + t) * 4;
    atomicAdd(g + 0, a.x + bq.x);
    atomicAdd(g + 1, a.y + bq.y);
    atomicAdd(g + 2, a.z + bq.z);
    atomicAdd(g + 3, a.w + bq.w);
  }
}

// ============ k1b: normalize + bilinear blend -> q (bf16, [b][n][c]) ============
__global__ __launch_bounds__(256) void k1b_combine(const ushort* __restrict__ corner,
                                                   const float* __restrict__ ssqg,
                                                   const float* __restrict__ kps,
                                                   ushort* __restrict__ qbf) {
  const int n = blockIdx.x, b = blockIdx.y, c = threadIdx.x;
  const float kx = kps[((size_t)b * N_ + n) * 2 + 0];
  const float ky = kps[((size_t)b * N_ + n) * 2 + 1];
  int x0, y0, x1, y1; float fx, fy;
  src_geom(kx, ky, x0, y0, x1, y1, fx, fy);
  const float wa = (1.f - fx) * (1.f - fy), wb = (1.f - fx) * fy;
  const float wc = fx * (1.f - fy), wd = fx * fy;

  const float4 sq = *(const float4*)&ssqg[((size_t)b * N_ + n) * 4];
  const float r0 = 1.f / fmaxf(sqrtf(sq.x), EPS_);
  const float r1 = 1.f / fmaxf(sqrtf(sq.y), EPS_);
  const float r2 = 1.f / fmaxf(sqrtf(sq.z), EPS_);
  const float r3 = 1.f / fmaxf(sqrtf(sq.w), EPS_);

  const ushort4 cr = *(const ushort4*)&corner[(((size_t)b * C_ + c) * N_ + n) * 4];
  const float qv = wa * bf2f(cr.x) * r0 + wb * bf2f(cr.y) * r1 +
                   wc * bf2f(cr.z) * r2 + wd * bf2f(cr.w) * r3;
  qbf[((size_t)b * N_ + n) * C_ + c] = f2bf(qv);
}

// ============ k2: MFMA logits via global_load_lds; softmax partials + target logits ============
// grid (NCH, B_), block 256. sA/sB unpadded [row][64k] bf16, XOR chunk swizzle in global addr.
__global__ __launch_bounds__(256) void k2_mfma(const ushort* __restrict__ trgT,
                                               const ushort* __restrict__ qbf,
                                               const float* __restrict__ sclg,
                                               const float* __restrict__ kps_trg,
                                               const int* __restrict__ mask,
                                               float2* __restrict__ part,
                                               float* __restrict__ tacc) {
  const int t = threadIdx.x;
  const int mb = blockIdx.x, b = blockIdx.y;
  const int m0 = mb * 128;
  const int wave = t >> 6, lane = t & 63;
  const int wn = wave >> 1, wm = wave & 1;
  const int lg = lane >> 4, ln = lane & 15;

  __shared__ __align__(16) short sA[128 * BKK];  // 16 KB, [n][64k]
  __shared__ __align__(16) short sB[128 * BKK];  // 16 KB, [m][64k]
  __shared__ float scl[128];
  __shared__ float2 lser[128 * 2];
  __shared__ __align__(16) int   tidx[128][4];
  __shared__ __align__(16) float tw[128][4];

  floatx4 acc[4][4];
#pragma unroll
  for (int i = 0; i < 4; i++)
#pragma unroll
    for (int j = 0; j < 4; j++) acc[i][j] = (floatx4)0.f;

  if (t < 128) {
    scl[t] = sclg[(size_t)b * M_ + m0 + t];
    const float kx = kps_trg[((size_t)b * N_ + t) * 2 + 0];
    const float ky = kps_trg[((size_t)b * N_ + t) * 2 + 1];
    const float gx = kx * (1.f / 16.f), gy = ky * (1.f / 16.f);
    const int x0 = (int)fminf(fmaxf(floorf(gx), 0.f), 63.f);
    const int y0 = (int)fminf(fmaxf(floorf(gy), 0.f), 63.f);
    const int x1 = min(x0 + 1, 63), y1 = min(y0 + 1, 63);
    const float x0f = (float)x0, x1f = (float)x1, y0f = (float)y0, y1f = (float)y1;
    const float mk = (mask[(size_t)b * N_ + t] != 0) ? 1.f : 0.f;
    tidx[t][0] = y0 * WF + x0; tw[t][0] = (x1f - gx) * (y1f - gy) * mk;
    tidx[t][1] = y1 * WF + x0; tw[t][1] = (x1f - gx) * (gy - y0f) * mk;
    tidx[t][2] = y0 * WF + x1; tw[t][2] = (gx - x0f) * (y1f - gy) * mk;
    tidx[t][3] = y1 * WF + x1; tw[t][3] = (gx - x0f) * (gy - y0f) * mk;
  }

  const char* qb = (const char*)(qbf + (size_t)b * N_ * C_);
  const char* tb = (const char*)(trgT + ((size_t)b * M_ + m0) * C_);

  for (int k0 = 0; k0 < C_; k0 += BKK) {
#pragma unroll
    for (int ii = 0; ii < 4; ii++) {
      const int inst = wave * 4 + ii;
      const int flat = inst * 64 + lane;
      const int r = flat >> 3, cs = flat & 7;       // row (n or m), stored chunk
      const int clog = cs ^ (r & 7);                // logical 16B chunk in row
      const int goff = r * 512 + k0 * 2 + clog * 16;
      gl2lds16(qb + goff, &sA[inst * 512]);
      gl2lds16(tb + goff, &sB[inst * 512]);
    }
    __syncthreads();
#pragma unroll
    for (int kk = 0; kk < 2; kk++) {
      short8 af[4], bfr[4];
#pragma unroll
      for (int i = 0; i < 4; i++) {
        const int n = wn * 64 + i * 16 + ln;
        af[i] = *(const short8*)&sA[n * BKK + (((kk * 4 + lg) ^ (n & 7)) << 3)];
      }
#pragma unroll
      for (int j = 0; j < 4; j++) {
        const int m = wm * 64 + j * 16 + ln;
        bfr[j] = *(const short8*)&sB[m * BKK + (((kk * 4 + lg) ^ (m & 7)) << 3)];
      }
#pragma unroll
      for (int i = 0; i < 4; i++)
#pragma unroll
        for (int j = 0; j < 4; j++)
          acc[i][j] = __builtin_amdgcn_mfma_f32_16x16x32_bf16(af[i], bfr[j], acc[i][j], 0, 0, 0);
    }
    __syncthreads();
  }

  float scj[4];
#pragma unroll
  for (int j = 0; j < 4; j++) scj[j] = scl[wm * 64 + j * 16 + ln];
#pragma unroll
  for (int i = 0; i < 4; i++)
#pragma unroll
    for (int j = 0; j < 4; j++) acc[i][j] *= scj[j];

#pragma unroll
  for (int i = 0; i < 4; i++) {
#pragma unroll
    for (int r = 0; r < 4; r++) {
      float mx = fmaxf(fmaxf(acc[i][0][r], acc[i][1][r]), fmaxf(acc[i][2][r], acc[i][3][r]));
#pragma unroll
      for (int msk = 1; msk < 16; msk <<= 1) mx = fmaxf(mx, __shfl_xor(mx, msk, 64));
      float sm = __expf(acc[i][0][r] - mx) + __expf(acc[i][1][r] - mx) +
                 __expf(acc[i][2][r] - mx) + __expf(acc[i][3][r] - mx);
#pragma unroll
      for (int msk = 1; msk < 16; msk <<= 1) sm += __shfl_xor(sm, msk, 64);
      if (ln == 0) lser[(wn * 64 + i * 16 + lg * 4 + r) * 2 + wm] = make_float2(mx, sm);

      const int n = wn * 64 + i * 16 + lg * 4 + r;
      const int4  id4 = *(const int4*)&tidx[n][0];
      const float4 w4 = *(const float4*)&tw[n][0];
      const int   ida[4] = {id4.x, id4.y, id4.z, id4.w};
      const float wwa[4] = {w4.x, w4.y, w4.z, w4.w};
#pragma unroll
      for (int j = 0; j < 4; j++) {
        const int mg = m0 + wm * 64 + j * 16 + ln;
        const float lv = acc[i][j][r];
#pragma unroll
        for (int cc = 0; cc < 4; cc++)
          if (ida[cc] == mg && wwa[cc] != 0.f)
            atomicAdd(&tacc[(size_t)b * N_ + n], wwa[cc] * lv);
      }
    }
  }
  __syncthreads();
  if (t < 128) {
    const float2 u = lser[t * 2 + 0], v = lser[t * 2 + 1];
    const float M = fmaxf(u.x, v.x);
    const float S = u.y * __expf(u.x - M) + v.y * __expf(v.x - M);
    part[((size_t)b * N_ + t) * NCH + mb] = make_float2(M, S);
  }
}

// ============ k4: per-(b,n) loss combine + masked-sum atomics ============
__global__ __launch_bounds__(128) void k4_comb(const float2* __restrict__ part,
                                               const float* __restrict__ tacc,
                                               const float* __restrict__ kps_trg,
                                               const int* __restrict__ mask,
                                               float* __restrict__ gs) {
  const int b = blockIdx.x, t = threadIdx.x;  // t = n
  const float2* p = part + ((size_t)b * N_ + t) * NCH;
  float M = -INFINITY;
#pragma unroll 8
  for (int c = 0; c < NCH; c++) M = fmaxf(M, p[c].x);
  float S = 0.f;
#pragma unroll 8
  for (int c = 0; c < NCH; c++) S += p[c].y * __expf(p[c].x - M);
  const float lse = M + logf(S);

  const float kx = kps_trg[((size_t)b * N_ + t) * 2 + 0];
  const float ky = kps_trg[((size_t)b * N_ + t) * 2 + 1];
  const float gx = kx * (1.f / 16.f), gy = ky * (1.f / 16.f);
  const int x0 = (int)fminf(fmaxf(floorf(gx), 0.f), 63.f);
  const int y0 = (int)fminf(fmaxf(floorf(gy), 0.f), 63.f);
  const int x1 = min(x0 + 1, 63), y1 = min(y0 + 1, 63);
  const float mk = (mask[(size_t)b * N_ + t] != 0) ? 1.f : 0.f;
  const float wsum = (float)(x1 - x0) * (float)(y1 - y0) * mk;

  float loss = wsum * lse - tacc[(size_t)b * N_ + t];
  float cnt = mk;
  loss = wave_sum(loss);
  cnt = wave_sum(cnt);
  __shared__ float sl[2], sc2[2];
  if ((t & 63) == 0) { sl[t >> 6] = loss; sc2[t >> 6] = cnt; }
  __syncthreads();
  if (t == 0) {
    atomicAdd(&gs[0], sl[0] + sl[1]);
    atomicAdd(&gs[1], sc2[0] + sc2[1]);
  }
}

__global__ void k5_final(const float* __restrict__ gs, float* __restrict__ out) {
  out[0] = gs[0] / fmaxf(gs[1], 1.f);
}

extern "C" void kernel_launch(void* const* d_in, const int* in_sizes, int n_in,
                              void* d_out, int out_size, void* d_ws, size_t ws_size,
                              hipStream_t stream) {
  const float* feats_src = (const float*)d_in[0];
  const float* feats_trg = (const float*)d_in[1];
  const float* kps_src   = (const float*)d_in[2];
  const float* kps_trg   = (const float*)d_in[3];
  const int*   kps_mask  = (const int*)d_in[4];
  float* out = (float*)d_out;

  // ws layout (bytes):
  //   0         ssqg   : B*N*4 floats   = 65536
  //   65536     tacc   : B*N floats     = 16384
  //   81920     gs     : 2 floats
  //   82432     corner : B*C*N*4 ushort = 8388608
  //   8471040   qbf    : B*N*C ushort   = 2097152
  //   10568192  part   : B*N*NCH float2 = 1048576
  //   16777216  sclg   : B*M floats     = 524288
  //   33554432  trgT   : B*M*C ushort   = 67108864   (ends ~100.7 MB; ws is 512 MiB)
  char* wsb = (char*)d_ws;
  float*  ssqg   = (float*)(wsb + 0);
  float*  tacc   = (float*)(wsb + 65536);
  float*  gs     = (float*)(wsb + 81920);
  ushort* corner = (ushort*)(wsb + 82432);
  ushort* qbf    = (ushort*)(wsb + 8471040);
  float2* part   = (float2*)(wsb + 10568192);
  float*  sclg   = (float*)(wsb + 16777216);
  ushort* trgT   = (ushort*)(wsb + 33554432);

  hipMemsetAsync(wsb, 0, 81928, stream);  // zero ssqg + tacc + gs

  k0_trgT<<<dim3(M_ / TCH, B_), 256, 0, stream>>>(feats_trg, trgT, sclg);
  k1a_stage<<<dim3(C_ / 2, B_), 256, 0, stream>>>(feats_src, kps_src, corner, ssqg);
  k1b_combine<<<dim3(N_, B_), 256, 0, stream>>>(corner, ssqg, kps_src, qbf);
  k2_mfma<<<dim3(NCH, B_), 256, 0, stream>>>(trgT, qbf, sclg, kps_trg, kps_mask, part, tacc);
  k4_comb<<<dim3(B_), 128, 0, stream>>>(part, tacc, kps_trg, kps_mask, gs);
  k5_final<<<1, 1, 0, stream>>>(gs, out);
}